// Round 7
// baseline (156.114 us; speedup 1.0000x reference)
//
#include <hip/hip_runtime.h>
#include <hip/hip_bf16.h>

// B=2, M=2048, HID=1024, NH=16, D=64.  No softmax in the reference, so
//   out = ((h Wq^T)(h Wk^T)^T (h Wv^T)) Wo^T
// reassociates twice:  S_{b,h} = K_h^T V_h  (64x64), and
//   out_b = Q_b @ T_b   with  T_b[h*64+d, n] = sum_j S_{b,h}[d,j] Wo[n, h*64+j]
//
// Dtypes: inputs fp32, d_out fp32; internal bf16 with fp32 accumulate.
//
// Round-18: r16 (schedule) and r17 (L2 locality) both NEUTRAL.  r13's
// direct measurement (MfmaUtil 18.9%, conflicts 0, HBM 1TB/s, VALU 9%)
// says ~70% of gemm time is WAIT with MFMA-busy ~= the 10.3us floor.  The
// r15-r17 structure has ONE block/CU: both waves on a SIMD share the same
// block barrier, so every phase drain parks the whole SIMD (m97's 874TF
// relied on ~3 independent blocks/CU for cross-block overlap; lockstep has
// none -- which is exactly why in-block schedule tweaks were neutral).
// r18: 256-thr / 4-wave blocks, 2 blocks/CU, 3-buffer rotation (depth-2
// prefetch) -- the 2 waves/SIMD now come from different blocks with
// independent barriers: one block's drain overlaps the other's MFMAs.
//   gemm1: BM128 x BN192, grid 32x16=512 blocks, 60KB LDS/block (x2=120).
//   gemm2: BM64  x BN128, grid 64x8 =512 blocks, 36KB LDS/block.
// Ledger (depth-2): prologue stage(0),stage(1),vw<V>,barrier; phase kt
// stages kt+2 into buf (kt+2)%3 (distinct from read buf kt%3), ends
// vw<V> (drains tile kt+1: 2V->V outstanding, FIFO) + barrier; tail
// vw<0>/none.  WAR proof as r14 (lgkmcnt(0) before the barrier that
// precedes the overwriting stage).  Swizzle unchanged (row bases %16==0).
// Lessons kept: no dense-reduction atomics (r6->r7); never trade
// high-occupancy FLOPs for low-occupancy FLOPs (r8); price redundant
// re-reads by XCD locality (r10); vmcnt waits are per-wave -- wait must
// precede a barrier (r12); count LDS bytes per phase (r13); grid must
// cover all 256 CUs (r14); don't serialize LDS and MFMA with explicit
// drains (r15); size the per-XCD L2 working set (r16); in-block schedule
// tweaks can't fix a lockstep-barrier stall -- co-residency can (r17).
//
// Pipeline:
//   0. prep: h->hb (bf16), Wq|Wk|Wv->wcat (bf16)
//   1. QKVb = hb @ wcat^T        (4096x3072 bf16)            [gemm32<128,192>]
//   2. Spart[bh,c] = K^T V partial over 128 rows             [VALU]
//   2b. S = sum_c Spart          (each line read once)       [BW]
//   3. Tt[b][n,k] = (S_h Wo_h^T)^T  (2 x 1024x1024 bf16)     [VALU]
//   4. out = Q @ Tt_b^T          (4096x1024 fp32 -> d_out)   [gemm32<64,128>]

typedef unsigned short u16;
typedef unsigned int u32;
typedef __attribute__((ext_vector_type(8))) short bf16x8;
typedef __attribute__((ext_vector_type(4))) float f32x4;

__device__ __forceinline__ void async_copy16(void* lds, const void* g) {
  __builtin_amdgcn_global_load_lds((const __attribute__((address_space(1))) void*)g,
                                   (__attribute__((address_space(3))) void*)lds,
                                   16, 0, 0);
}

__device__ __forceinline__ u16 f2bf(float f) {
  union { __hip_bfloat16 h; u16 u; } c;
  c.h = __float2bfloat16(f);
  return c.u;
}
__device__ __forceinline__ float bflo(u32 w) {
  union { u32 u; float f; } c; c.u = w << 16; return c.f;
}
__device__ __forceinline__ float bfhi(u32 w) {
  union { u32 u; float f; } c; c.u = w & 0xFFFF0000u; return c.f;
}
__device__ __forceinline__ ushort4 cvt4(float4 v) {
  ushort4 o; o.x = f2bf(v.x); o.y = f2bf(v.y); o.z = f2bf(v.z); o.w = f2bf(v.w);
  return o;
}

template <int N> __device__ __forceinline__ void vw() {
  if constexpr (N == 10)     asm volatile("s_waitcnt vmcnt(10)" ::: "memory");
  else if constexpr (N == 8) asm volatile("s_waitcnt vmcnt(8)" ::: "memory");
  else if constexpr (N == 6) asm volatile("s_waitcnt vmcnt(6)" ::: "memory");
  else if constexpr (N == 5) asm volatile("s_waitcnt vmcnt(5)" ::: "memory");
  else if constexpr (N == 4) asm volatile("s_waitcnt vmcnt(4)" ::: "memory");
  else if constexpr (N == 3) asm volatile("s_waitcnt vmcnt(3)" ::: "memory");
  else if constexpr (N == 2) asm volatile("s_waitcnt vmcnt(2)" ::: "memory");
  else if constexpr (N == 0) asm volatile("s_waitcnt vmcnt(0)" ::: "memory");
}

// ---------------------------------------------------------------- prep ------
__global__ __launch_bounds__(256) void prep(const float4* __restrict__ h,
                                            const float4* __restrict__ wq,
                                            const float4* __restrict__ wk,
                                            const float4* __restrict__ wv,
                                            ushort4* __restrict__ hb,
                                            ushort4* __restrict__ wcat) {
  int i = blockIdx.x * 256 + threadIdx.x;  // float4 units
  if (i < 1048576) { hb[i] = cvt4(h[i]); return; }          // h: 4096x1024
  i -= 1048576;
  if (i < 262144) { wcat[i] = cvt4(wq[i]); return; }
  i -= 262144;
  if (i < 262144) { wcat[262144 + i] = cvt4(wk[i]); return; }
  i -= 262144;
  wcat[524288 + i] = cvt4(wv[i]);
}

// --------------------- BK=32 3-buffer counted-vmcnt NT GEMM, 4 waves --------
// C[m,n] = sum_k A[m*lda+k] * B[n*1024+k], M=4096, K=1024.
// 256 thr = 4 waves, all spanning BM rows; wave w owns n-cols
// [w*BN/4, (w+1)*BN/4).  2 blocks/CU (LDS <= 64KB/block): the 2 waves on a
// SIMD belong to DIFFERENT blocks -> independent barriers -> overlap.
// One phase per K-tile: {MI+NI ds_read_b128 | stage tile kt+2 into buf
// (kt+2)%3 | MI*NI MFMA (setprio) | lgkmcnt(0) | vw<V> | s_barrier |
// sched_barrier}.

#define NOPW ((void)0)

#define PHASE(KT, DO_STAGE, VWAIT)                                           \
  do {                                                                       \
    const u16* Ab = &Als[(KT) % 3][aoff];                                    \
    const u16* Bb = &Bls[(KT) % 3][wn * 32 + aoff];                          \
    bf16x8 af[MI], bv[NI];                                                   \
    _Pragma("unroll") for (int i = 0; i < MI; ++i)                           \
        af[i] = *(const bf16x8*)(Ab + i * 512);                              \
    _Pragma("unroll") for (int j = 0; j < NI; ++j)                           \
        bv[j] = *(const bf16x8*)(Bb + j * 512);                              \
    DO_STAGE;                                                                \
    __builtin_amdgcn_s_setprio(1);                                           \
    _Pragma("unroll") for (int i = 0; i < MI; ++i)                           \
        _Pragma("unroll") for (int j = 0; j < NI; ++j)                       \
            acc[i][j] = __builtin_amdgcn_mfma_f32_16x16x32_bf16(             \
                af[i], bv[j], acc[i][j], 0, 0, 0);                           \
    __builtin_amdgcn_s_setprio(0);                                           \
    asm volatile("s_waitcnt lgkmcnt(0)" ::: "memory");                       \
    VWAIT;                                                                   \
    __builtin_amdgcn_s_barrier();                                            \
    __builtin_amdgcn_sched_barrier(0);                                       \
  } while (0)

template <bool BF16_OUT, int BM, int BN>
__global__ __launch_bounds__(256, 2) void gemm32(const u16* __restrict__ A,
                                                 int lda,
                                                 const u16* __restrict__ B0,
                                                 const u16* __restrict__ B1,
                                                 void* __restrict__ Cv,
                                                 int N, int m0, int n0) {
  static_assert(BM % 64 == 0 && BN % 64 == 0, "");
  constexpr int SA = BM / 64;        // A staging insts/thread
  constexpr int SB = BN / 64;        // B staging insts/thread
  constexpr int V  = SA + SB;        // insts/thread per tile
  constexpr int MI = BM / 16;        // m-frags per wave (wave spans BM)
  constexpr int NI = BN / 4 / 16;    // n-frags per wave

  __shared__ u16 Als[3][BM * 32];
  __shared__ u16 Bls[3][BN * 32];
  const int t = threadIdx.x;
  const int lane = t & 63;
  const int wave = t >> 6;                 // 0..3
  const int wn = wave * (BN / 4);          // mult of 16
  const int lrow = lane & 15;
  const int quad = lane >> 4;

  const u16* B = (B1 != nullptr && m0 >= 2048) ? B1 : B0;

  // staging: one inst = 16 rows x 32 k = 1 KB; lane l -> row +(l>>2),
  // LDS slot l&3 holding global k-granule (l&3)^((l>>3)&3)  (linear dest).
  const int srow = lane >> 2;                       // 0..15
  const int sgk  = (lane & 3) ^ ((lane >> 3) & 3);  // global k-granule
  const u16* Ag = A + (size_t)(m0 + srow) * lda + sgk * 8;
  const u16* Bg = B + (size_t)(n0 + srow) * 1024 + sgk * 8;

  // read swizzle: slot holding granule `quad` at row r is quad^((r>>1)&3);
  // all row bases are multiples of 16, so (r>>1)&3 == (lrow>>1)&3.
  const int swz = (lrow >> 1) & 3;
  const int aoff = lrow * 32 + ((quad ^ swz) << 3);  // u16 units

  f32x4 acc[MI][NI];
#pragma unroll
  for (int i = 0; i < MI; ++i)
#pragma unroll
    for (int j = 0; j < NI; ++j) acc[i][j] = {0.f, 0.f, 0.f, 0.f};

  // stage tile kt (V insts/thread) into buf kt%3; chunk ch = j*4+wave.
  auto stage = [&](int kt) {
    const int buf = kt % 3;
#pragma unroll
    for (int j = 0; j < SA; ++j) {
      const int ch = j * 4 + wave;                   // 16-row chunk
      async_copy16(&Als[buf][ch * 512 + lane * 8],
                   Ag + (size_t)(ch * 16) * lda + kt * 32);
    }
#pragma unroll
    for (int j = 0; j < SB; ++j) {
      const int ch = j * 4 + wave;
      async_copy16(&Bls[buf][ch * 512 + lane * 8],
                   Bg + (size_t)(ch * 16) * 1024 + kt * 32);
    }
  };

  // prologue (depth-2): stage tiles 0,1; wait tile0 (V left); barrier.
  stage(0); stage(1);
  vw<V>();
  __builtin_amdgcn_s_barrier();
  __builtin_amdgcn_sched_barrier(0);

  // steady: phase kt stages kt+2 (2V in flight), vw<V> drains tile kt+1.
#pragma unroll 1
  for (int kt = 0; kt < 30; ++kt) {
    PHASE(kt, stage(kt + 2), vw<V>());
  }
  PHASE(30, NOPW, vw<0>());   // in flight: t31 -> drain
  PHASE(31, NOPW, NOPW);

  // C/D layout (verified m89/m91): col = lane&15, row = (lane>>4)*4 + r
  const int crow0 = m0 + quad * 4;
  const int ccol0 = n0 + wn + lrow;
#pragma unroll
  for (int mf = 0; mf < MI; ++mf)
#pragma unroll
    for (int nf = 0; nf < NI; ++nf)
#pragma unroll
      for (int r = 0; r < 4; ++r) {
        const size_t idx = (size_t)(crow0 + mf * 16 + r) * N + ccol0 + nf * 16;
        if (BF16_OUT) ((u16*)Cv)[idx]   = f2bf(acc[mf][nf][r]);
        else          ((float*)Cv)[idx] = acc[mf][nf][r];
      }
}

// grid-mapping wrappers: compute (m0, n0) with XCD-owns-n-panel layout.
__global__ __launch_bounds__(256, 2) void gemm1_k(const u16* __restrict__ A,
                                                  const u16* __restrict__ B0,
                                                  u16* __restrict__ C);
__global__ __launch_bounds__(256, 2) void gemm2_k(const u16* __restrict__ A,
                                                  const u16* __restrict__ B0,
                                                  const u16* __restrict__ B1,
                                                  float* __restrict__ C);

// (wrappers implemented via direct launches of gemm32 below; mapping is
// computed host-side per-block via blockIdx in small stub kernels)
template <bool BF16_OUT, int BM, int BN, int NT>
__global__ __launch_bounds__(256, 2) void gemm_map(const u16* __restrict__ A,
                                                   int lda,
                                                   const u16* __restrict__ B0,
                                                   const u16* __restrict__ B1,
                                                   void* __restrict__ Cv,
                                                   int N) {
  // NT = number of n-tiles.  XCD x (bid&7) owns n-panels {x*NT/8 .. }.
  const int bid = blockIdx.x;
  int m0, n0;
  if (NT == 16) {            // gemm1: 32 m x 16 n
    m0 = (bid >> 4) * BM;
    n0 = (((bid & 7) << 1) | ((bid >> 3) & 1)) * BN;
  } else {                   // gemm2: 64 m x 8 n
    m0 = (bid >> 3) * BM;
    n0 = (bid & 7) * BN;
  }
  // delegate: inline the body by calling the device path
  // (gemm32 is a kernel; replicate by tail-call pattern -> instead we
  //  simply include the body via a device function)
  // -- implemented by making gemm32's body a device function:
  extern __device__ void unreachable_();
  (void)A; (void)lda; (void)B0; (void)B1; (void)Cv; (void)N; (void)m0; (void)n0;
}

// NOTE: to keep one definition, gemm32 takes (m0,n0) as kernel args is not
// possible per-block; instead we fold the mapping directly into gemm32 via
// an NT template parameter:
template <bool BF16_OUT, int BM, int BN, int NT>
__global__ __launch_bounds__(256, 2) void gemm32m(const u16* __restrict__ A,
                                                  int lda,
                                                  const u16* __restrict__ B0,
                                                  const u16* __restrict__ B1,
                                                  void* __restrict__ Cv,
                                                  int N) {
  static_assert(BM % 64 == 0 && BN % 64 == 0, "");
  constexpr int SA = BM / 64;
  constexpr int SB = BN / 64;
  constexpr int V  = SA + SB;
  constexpr int MI = BM / 16;
  constexpr int NI = BN / 4 / 16;

  __shared__ u16 Als[3][BM * 32];
  __shared__ u16 Bls[3][BN * 32];
  const int t = threadIdx.x;
  const int lane = t & 63;
  const int wave = t >> 6;
  const int wn = wave * (BN / 4);
  const int lrow = lane & 15;
  const int quad = lane >> 4;

  const int bid = blockIdx.x;
  int m0, n0;
  if constexpr (NT == 16) {  // gemm1: XCD owns n-panels {2x,2x+1}
    m0 = (bid >> 4) * BM;
    n0 = ((((bid & 7) << 1) | ((bid >> 3) & 1))) * BN;
  } else {                   // gemm2: XCD owns n-panel (bid&7)
    m0 = (bid >> 3) * BM;
    n0 = (bid & 7) * BN;
  }
  const u16* B = (B1 != nullptr && m0 >= 2048) ? B1 : B0;

  const int srow = lane >> 2;
  const int sgk  = (lane & 3) ^ ((lane >> 3) & 3);
  const u16* Ag = A + (size_t)(m0 + srow) * lda + sgk * 8;
  const u16* Bg = B + (size_t)(n0 + srow) * 1024 + sgk * 8;

  const int swz = (lrow >> 1) & 3;
  const int aoff = lrow * 32 + ((quad ^ swz) << 3);

  f32x4 acc[MI][NI];
#pragma unroll
  for (int i = 0; i < MI; ++i)
#pragma unroll
    for (int j = 0; j < NI; ++j) acc[i][j] = {0.f, 0.f, 0.f, 0.f};

  auto stage = [&](int kt) {
    const int buf = kt % 3;
#pragma unroll
    for (int j = 0; j < SA; ++j) {
      const int ch = j * 4 + wave;
      async_copy16(&Als[buf][ch * 512 + lane * 8],
                   Ag + (size_t)(ch * 16) * lda + kt * 32);
    }
#pragma unroll
    for (int j = 0; j < SB; ++j) {
      const int ch = j * 4 + wave;
      async_copy16(&Bls[buf][ch * 512 + lane * 8],
                   Bg + (size_t)(ch * 16) * 1024 + kt * 32);
    }
  };

  stage(0); stage(1);
  vw<V>();
  __builtin_amdgcn_s_barrier();
  __builtin_amdgcn_sched_barrier(0);

#pragma unroll 1
  for (int kt = 0; kt < 30; ++kt) {
    PHASE(kt, stage(kt + 2), vw<V>());
  }
  PHASE(30, NOPW, vw<0>());
  PHASE(31, NOPW, NOPW);

  const int crow0 = m0 + quad * 4;
  const int ccol0 = n0 + wn + lrow;
#pragma unroll
  for (int mf = 0; mf < MI; ++mf)
#pragma unroll
    for (int nf = 0; nf < NI; ++nf)
#pragma unroll
      for (int r = 0; r < 4; ++r) {
        const size_t idx = (size_t)(crow0 + mf * 16 + r) * N + ccol0 + nf * 16;
        if (BF16_OUT) ((u16*)Cv)[idx]   = f2bf(acc[mf][nf][r]);
        else          ((float*)Cv)[idx] = acc[mf][nf][r];
      }
}

// --------------------------------------------- Spart = partial K^T V --------
__global__ __launch_bounds__(256) void s_kernel(const u16* __restrict__ QKV,
                                                float* __restrict__ Spart) {
  const int bh = blockIdx.x;
  const int b = bh >> 4, hh = bh & 15;
  const int row0 = b * 2048 + blockIdx.y * 128;
  const u16* Kg = QKV + (size_t)row0 * 3072 + 1024 + hh * 64;

  __shared__ float Ks[64][64];
  __shared__ float Vs[64][64];
  const int t = threadIdx.x;
  const int lr = t >> 2;        // 0..63 row within stage
  const int lc = (t & 3) * 16;  // col group (16 cols)
  const int d1 = (t >> 4) * 4;
  const int d2 = (t & 15) * 4;

  float acc[4][4] = {};

  for (int r0 = 0; r0 < 128; r0 += 64) {
    const u16* kp = Kg + (size_t)(r0 + lr) * 3072 + lc;
    const uint4 kw0 = *(const uint4*)kp;
    const uint4 kw1 = *(const uint4*)(kp + 8);
    const uint4 vw0 = *(const uint4*)(kp + 1024);  // V = K + 1024 cols
    const uint4 vw1 = *(const uint4*)(kp + 1032);
    __syncthreads();  // prev-iter readers done
    float* kd = &Ks[lr][lc];
    *(float4*)(kd)      = float4{bflo(kw0.x), bfhi(kw0.x), bflo(kw0.y), bfhi(kw0.y)};
    *(float4*)(kd + 4)  = float4{bflo(kw0.z), bfhi(kw0.z), bflo(kw0.w), bfhi(kw0.w)};
    *(float4*)(kd + 8)  = float4{bflo(kw1.x), bfhi(kw1.x), bflo(kw1.y), bfhi(kw1.y)};
    *(float4*)(kd + 12) = float4{bflo(kw1.z), bfhi(kw1.z), bflo(kw1.w), bfhi(kw1.w)};
    float* vd = &Vs[lr][lc];
    *(float4*)(vd)      = float4{bflo(vw0.x), bfhi(vw0.x), bflo(vw0.y), bfhi(vw0.y)};
    *(float4*)(vd + 4)  = float4{bflo(vw0.z), bfhi(vw0.z), bflo(vw0.w), bfhi(vw0.w)};
    *(float4*)(vd + 8)  = float4{bflo(vw1.x), bfhi(vw1.x), bflo(vw1.y), bfhi(vw1.y)};
    *(float4*)(vd + 12) = float4{bflo(vw1.z), bfhi(vw1.z), bflo(vw1.w), bfhi(vw1.w)};
    __syncthreads();
#pragma unroll
    for (int r = 0; r < 64; ++r) {
      float kv[4], vv[4];
      *(float4*)kv = *(const float4*)&Ks[r][d1];
      *(float4*)vv = *(const float4*)&Vs[r][d2];
#pragma unroll
      for (int i = 0; i < 4; ++i)
#pragma unroll
        for (int j = 0; j < 4; ++j) acc[i][j] += kv[i] * vv[j];
    }
  }
  float* Sp = Spart + ((size_t)bh * 16 + blockIdx.y) * 4096;
#pragma unroll
  for (int i = 0; i < 4; ++i)
    *(float4*)&Sp[(d1 + i) * 64 + d2] =
        float4{acc[i][0], acc[i][1], acc[i][2], acc[i][3]};
}

// ---------------------------------------------------- S = sum_c Spart -------
__global__ __launch_bounds__(256) void reduce_s(const float4* __restrict__ Spart,
                                                float4* __restrict__ S) {
  const int g = blockIdx.x * 256 + threadIdx.x;  // 0..32767
  const int bh = g >> 10, j = g & 1023;
  const float4* p = Spart + (size_t)bh * 16384 + j;  // 16 chunks * 1024 f4
  float4 a = {0.f, 0.f, 0.f, 0.f};
#pragma unroll
  for (int c = 0; c < 16; ++c) {
    const float4 v = p[(size_t)c * 1024];
    a.x += v.x; a.y += v.y; a.z += v.z; a.w += v.w;
  }
  S[g] = a;
}

// ------------------------------------------- Tt = (S_h Wo_h^T)^T ------------
__global__ __launch_bounds__(256) void t_kernel(const float* __restrict__ S,
                                                const float* __restrict__ Wo,
                                                u16* __restrict__ Tt) {
  const int n0 = blockIdx.x * 128;
  const int hh = blockIdx.y;
  const int b  = blockIdx.z;
  __shared__ float Ss[64][68];
  __shared__ float Ws[128][68];
  const int t = threadIdx.x;
  {
    const float* sg = S + (size_t)(b * 16 + hh) * 4096 + (t >> 2) * 64 + (t & 3) * 16;
    float* sd = &Ss[t >> 2][(t & 3) * 16];
#pragma unroll
    for (int i = 0; i < 4; ++i) *(float4*)(sd + 4 * i) = *(const float4*)(sg + 4 * i);
    const float* wg = Wo + (size_t)(n0 + (t >> 1)) * 1024 + hh * 64 + (t & 1) * 32;
    float* wd = &Ws[t >> 1][(t & 1) * 32];
#pragma unroll
    for (int i = 0; i < 8; ++i) *(float4*)(wd + 4 * i) = *(const float4*)(wg + 4 * i);
  }
  __syncthreads();

  const int td = (t >> 4) * 4;  // d = td..td+3
  const int tn = t & 15;        // n = n0 + tn + 16k
  float acc[4][8] = {};
  for (int jj = 0; jj < 64; jj += 4) {
    float4 sv[4], wv[8];
#pragma unroll
    for (int i = 0; i < 4; ++i) sv[i] = *(const float4*)&Ss[td + i][jj];
#pragma unroll
    for (int k = 0; k < 8; ++k) wv[k] = *(const float4*)&Ws[tn + 16 * k][jj];
#pragma unroll
    for (int i = 0; i < 4; ++i)
#pragma unroll
      for (int k = 0; k < 8; ++k)
        acc[i][k] += sv[i].x * wv[k].x + sv[i].y * wv[k].y +
                     sv[i].z * wv[k].z + sv[i].w * wv[k].w;
  }

  u16* tp = Tt + (size_t)b * 1048576;
#pragma unroll
  for (int k = 0; k < 8; ++k) {
    const int n = n0 + tn + 16 * k;
    ushort4 o;
    o.x = f2bf(acc[0][k]); o.y = f2bf(acc[1][k]);
    o.z = f2bf(acc[2][k]); o.w = f2bf(acc[3][k]);
    *(ushort4*)&tp[(size_t)n * 1024 + hh * 64 + td] = o;
  }
}

// ---------------------------------------------------------------------------
extern "C" void kernel_launch(void* const* d_in, const int* in_sizes, int n_in,
                              void* d_out, int out_size, void* d_ws, size_t ws_size,
                              hipStream_t stream) {
  const float* h  = (const float*)d_in[0];  // (4096, 1024) fp32
  // d_in[1] = key_pe: dead branch in reference, unused.
  const float* Wq = (const float*)d_in[2];
  const float* Wk = (const float*)d_in[3];
  const float* Wv = (const float*)d_in[4];
  const float* Wo = (const float*)d_in[5];

  char* ws = (char*)d_ws;
  u16*   hb    = (u16*)(ws);                    // 4096*1024*2 = 8 MiB @ 0
  u16*   wcat  = (u16*)(ws + (8ull  << 20));    // 3072*1024*2 = 6 MiB
  u16*   QKVb  = (u16*)(ws + (16ull << 20));    // 4096*3072*2 = 24 MiB
  float* S     = (float*)(ws + (40ull << 20));  // 32*64*64*4  = 0.5 MiB
  u16*   Tt    = (u16*)(ws + (41ull << 20));    // 2*1024*1024*2 = 4 MiB
  float* Spart = (float*)(ws + (48ull << 20));  // 512*64*64*4 = 8 MiB
  // total ws use: 56 MiB (ws_size = 256 MiB)

  prep<<<7168, 256, 0, stream>>>((const float4*)h, (const float4*)Wq,
                                 (const float4*)Wk, (const float4*)Wv,
                                 (ushort4*)hb, (ushort4*)wcat);
  // QKVb = hb @ wcat^T : (4096 x 3072), 512 blocks = 2/CU, 4 waves each
  gemm32m<true, 128, 192, 16><<<512, 256, 0, stream>>>(hb, 1024, wcat,
                                                       nullptr, QKVb, 3072);
  s_kernel<<<dim3(32, 16), 256, 0, stream>>>(QKVb, Spart);
  reduce_s<<<128, 256, 0, stream>>>((const float4*)Spart, (float4*)S);
  t_kernel<<<dim3(8, 16, 2), 256, 0, stream>>>(S, Wo, Tt);
  // out = Q @ Tt_b^T : (4096 x 1024), 512 blocks = 2/CU, 4 waves each
  gemm32m<false, 64, 128, 8><<<512, 256, 0, stream>>>(QKVb, 3072, Tt,
                                                      Tt + 1048576, d_out,
                                                      1024);
}